// Round 1
// baseline (4597.719 us; speedup 1.0000x reference)
//
#include <hip/hip_runtime.h>
#include <cmath>

#define T_DIM 2048
#define C_DIM 2048
#define NH    32
#define SS    64

// ---------------------------------------------------------------------------
// Kernel 1: token-shift prep.  sx = (ns? 0 : prev_token) - x ; xxx = x + sx*tmx
// ---------------------------------------------------------------------------
__global__ __launch_bounds__(256)
void prep_kernel(const float* __restrict__ x, const float* __restrict__ state,
                 const unsigned char* __restrict__ ns,
                 const float* __restrict__ tmx,
                 float* __restrict__ sx, float* __restrict__ xxx) {
    int i4 = blockIdx.x * 256 + threadIdx.x;          // over T*C/4
    if (i4 >= T_DIM * C_DIM / 4) return;
    int idx = i4 * 4;
    int t = idx >> 11;
    int c = idx & 2047;
    float4 xv = *(const float4*)(x + idx);
    float4 prev;
    if (ns[t]) {
        prev = make_float4(0.f, 0.f, 0.f, 0.f);
    } else if (t == 0) {
        prev = *(const float4*)(state + c);
    } else {
        prev = *(const float4*)(x + idx - C_DIM);
    }
    float4 tm = *(const float4*)(tmx + c);
    float4 s4, xx4;
    s4.x = prev.x - xv.x;  s4.y = prev.y - xv.y;
    s4.z = prev.z - xv.z;  s4.w = prev.w - xv.w;
    xx4.x = xv.x + s4.x * tm.x;  xx4.y = xv.y + s4.y * tm.y;
    xx4.z = xv.z + s4.z * tm.z;  xx4.w = xv.w + s4.w * tm.w;
    *(float4*)(sx + idx)  = s4;
    *(float4*)(xxx + idx) = xx4;
}

// ---------------------------------------------------------------------------
// Generic fp32 tiled GEMM: C[M,N] = epi(A[M,K] @ B[K,N]).
// BM=BN=64, BK=16, 256 threads, 4x4 micro-tile.
// EPI: 0 none, 1 tanh, 2 sigmoid, 3 +bias[col]
// M must be a multiple of 64, K a multiple of 16, N a multiple of 4.
// ---------------------------------------------------------------------------
template<int EPI>
__global__ __launch_bounds__(256)
void gemm_f32(const float* __restrict__ A, const float* __restrict__ B,
              const float* __restrict__ bias, float* __restrict__ C,
              int M, int N, int K) {
    __shared__ float As[16][65];   // [k][m], padded
    __shared__ float Bs[16][64];   // [k][n]
    int tid = threadIdx.x;
    int tx = tid & 15;             // output col group
    int ty = tid >> 4;             // output row group
    int m0 = blockIdx.y * 64;
    int n0 = blockIdx.x * 64;
    int arow = tid >> 2;           // 0..63
    int acol = (tid & 3) << 2;     // 0,4,8,12
    int brow = tid >> 4;           // 0..15
    int bcol = (tid & 15) << 2;    // 0..60

    float acc[4][4] = {};

    for (int k0 = 0; k0 < K; k0 += 16) {
        float4 a4 = *(const float4*)(A + (size_t)(m0 + arow) * K + k0 + acol);
        As[acol + 0][arow] = a4.x;
        As[acol + 1][arow] = a4.y;
        As[acol + 2][arow] = a4.z;
        As[acol + 3][arow] = a4.w;
        float4 b4 = make_float4(0.f, 0.f, 0.f, 0.f);
        if (n0 + bcol < N)
            b4 = *(const float4*)(B + (size_t)(k0 + brow) * N + n0 + bcol);
        *(float4*)&Bs[brow][bcol] = b4;
        __syncthreads();
        #pragma unroll
        for (int kk = 0; kk < 16; ++kk) {
            float a[4], b[4];
            #pragma unroll
            for (int i = 0; i < 4; ++i) a[i] = As[kk][ty * 4 + i];
            #pragma unroll
            for (int j = 0; j < 4; ++j) b[j] = Bs[kk][tx * 4 + j];
            #pragma unroll
            for (int i = 0; i < 4; ++i)
                #pragma unroll
                for (int j = 0; j < 4; ++j)
                    acc[i][j] = fmaf(a[i], b[j], acc[i][j]);
        }
        __syncthreads();
    }

    #pragma unroll
    for (int i = 0; i < 4; ++i) {
        int row = m0 + ty * 4 + i;
        #pragma unroll
        for (int j = 0; j < 4; ++j) {
            int col = n0 + tx * 4 + j;
            if (col < N) {
                float v = acc[i][j];
                if (EPI == 1) v = tanhf(v);
                else if (EPI == 2) v = 1.f / (1.f + __expf(-v));
                else if (EPI == 3) v = v + bias[col];
                C[(size_t)row * N + col] = v;
            }
        }
    }
}

// ---------------------------------------------------------------------------
// Kernel 3: LoRA combine.  m_n[t,c] = sum_l mtl[t,n*32+l]*W2[n,l,c];
// x?[t,c] = x + sx*(time_maa_? + m_n)
// ---------------------------------------------------------------------------
__global__ __launch_bounds__(256)
void maa_combine(const float* __restrict__ x, const float* __restrict__ sx,
                 const float* __restrict__ mtl, const float* __restrict__ W2,
                 const float* __restrict__ tmr, const float* __restrict__ tmk,
                 const float* __restrict__ tmv, const float* __restrict__ tmw,
                 const float* __restrict__ tmg,
                 float* __restrict__ xr, float* __restrict__ xk,
                 float* __restrict__ xv, float* __restrict__ xw,
                 float* __restrict__ xg) {
    int t = blockIdx.x;
    __shared__ float ml[160];
    if (threadIdx.x < 160) ml[threadIdx.x] = mtl[t * 160 + threadIdx.x];
    __syncthreads();
    for (int c = threadIdx.x; c < C_DIM; c += 256) {
        float a0 = 0.f, a1 = 0.f, a2 = 0.f, a3 = 0.f, a4 = 0.f;
        #pragma unroll 8
        for (int l = 0; l < 32; ++l) {
            a0 = fmaf(ml[l],       W2[(size_t)(l)       * C_DIM + c], a0);
            a1 = fmaf(ml[32 + l],  W2[(size_t)(32 + l)  * C_DIM + c], a1);
            a2 = fmaf(ml[64 + l],  W2[(size_t)(64 + l)  * C_DIM + c], a2);
            a3 = fmaf(ml[96 + l],  W2[(size_t)(96 + l)  * C_DIM + c], a3);
            a4 = fmaf(ml[128 + l], W2[(size_t)(128 + l) * C_DIM + c], a4);
        }
        size_t idx = (size_t)t * C_DIM + c;
        float xval = x[idx], sxv = sx[idx];
        xr[idx] = xval + sxv * (tmr[c] + a0);
        xk[idx] = xval + sxv * (tmk[c] + a1);
        xv[idx] = xval + sxv * (tmv[c] + a2);
        xw[idx] = xval + sxv * (tmw[c] + a3);
        xg[idx] = xval + sxv * (tmg[c] + a4);
    }
}

// ---------------------------------------------------------------------------
// Kernel 5: per-head sequential scan.  32 blocks (heads) x 64 threads (v-col).
// Lane v holds state column s[k=0..63][v] in registers.
// ---------------------------------------------------------------------------
__global__ __launch_bounds__(64)
void scan_kernel(const float* __restrict__ r, const float* __restrict__ k0,
                 const float* __restrict__ v0, const float* __restrict__ dec,
                 const float* __restrict__ state,
                 const unsigned char* __restrict__ ns,
                 float* __restrict__ y0, float* __restrict__ outstate) {
    int h = blockIdx.x;
    int v = threadIdx.x;
    int hk = h >> 2;             // reps = H/H_KV = 4
    float s[64];
    #pragma unroll
    for (int k = 0; k < 64; ++k)
        s[k] = state[C_DIM + h * 4096 + k * 64 + v];

    __shared__ float r_s[64], ew_s[64], kk_s[64];

    for (int t = 0; t < T_DIM; ++t) {
        float dv = dec[(size_t)t * 2048 + h * 64 + v];
        float lw = fmaxf(-__expf(dv), -5.f);
        float ew = __expf(lw);
        r_s[v]  = r[(size_t)t * 2048 + h * 64 + v];
        ew_s[v] = ew;
        kk_s[v] = k0[(size_t)t * 512 + hk * 64 + v] * (1.f - ew);
        __syncthreads();
        if (ns[t]) {
            #pragma unroll
            for (int k = 0; k < 64; ++k) s[k] = 0.f;
        }
        float vv = v0[(size_t)t * 512 + hk * 64 + v];
        float o = 0.f;
        #pragma unroll
        for (int k = 0; k < 64; ++k) {
            float sk = fmaf(s[k], ew_s[k], kk_s[k] * vv);
            s[k] = sk;
            o = fmaf(r_s[k], sk, o);
        }
        y0[(size_t)t * 2048 + h * 64 + v] = o;
        __syncthreads();
    }
    #pragma unroll
    for (int k = 0; k < 64; ++k)
        outstate[C_DIM + h * 4096 + k * 64 + v] = s[k];
}

// ---------------------------------------------------------------------------
// Kernel 6a: y0 *= g (in place, float4)
// ---------------------------------------------------------------------------
__global__ __launch_bounds__(256)
void mulg_kernel(float* __restrict__ y0, const float* __restrict__ g) {
    int i4 = blockIdx.x * 256 + threadIdx.x;
    if (i4 >= T_DIM * C_DIM / 4) return;
    float4 a = *(float4*)(y0 + i4 * 4);
    float4 b = *(const float4*)(g + i4 * 4);
    a.x *= b.x; a.y *= b.y; a.z *= b.z; a.w *= b.w;
    *(float4*)(y0 + i4 * 4) = a;
}

// ---------------------------------------------------------------------------
// Kernel 6b: new_state row 0 = x[length-1]
// ---------------------------------------------------------------------------
__global__ __launch_bounds__(256)
void state0_kernel(const float* __restrict__ x, const int* __restrict__ len,
                   float* __restrict__ outstate) {
    int c = blockIdx.x * 256 + threadIdx.x;
    if (c < C_DIM)
        outstate[c] = x[(size_t)(len[0] - 1) * C_DIM + c];
}

// ---------------------------------------------------------------------------
extern "C" void kernel_launch(void* const* d_in, const int* in_sizes, int n_in,
                              void* d_out, int out_size, void* d_ws, size_t ws_size,
                              hipStream_t stream) {
    const float* x     = (const float*)d_in[0];
    const float* state = (const float*)d_in[1];
    const unsigned char* ns = (const unsigned char*)d_in[2];
    const int*   len   = (const int*)d_in[3];
    const float* tmx   = (const float*)d_in[4];
    const float* tmr   = (const float*)d_in[5];
    const float* tmk   = (const float*)d_in[6];
    const float* tmv   = (const float*)d_in[7];
    const float* tmw   = (const float*)d_in[8];
    const float* tmg   = (const float*)d_in[9];
    const float* W1    = (const float*)d_in[10];   // [C,160]
    const float* W2    = (const float*)d_in[11];   // [5,32,C]
    const float* tdec  = (const float*)d_in[12];   // [C]
    const float* Wd1   = (const float*)d_in[13];   // [C,64]
    const float* Wd2   = (const float*)d_in[14];   // [64,C]
    const float* Wq    = (const float*)d_in[15];
    const float* Wk    = (const float*)d_in[16];
    const float* Wv    = (const float*)d_in[17];
    const float* Wg    = (const float*)d_in[18];
    const float* Wo    = (const float*)d_in[19];

    float* out = (float*)d_out;            // [T*C] y, then [65*C] new_state
    float* outstate = out + (size_t)T_DIM * C_DIM;

    // workspace layout (floats), with aliasing:
    float* ws = (float*)d_ws;
    const size_t TC = (size_t)T_DIM * C_DIM;      // 4,194,304
    float* sx   = ws;                 // slot0: sx, later dec
    float* xxx  = ws + TC;            // slot1: xxx, later r
    float* mtl  = ws + 2 * TC;        // slot2: [T,160], later tw [T,64]
    float* xr   = ws + 2 * TC + 327680;   // slot3: xr, later y0
    float* xk   = xr + TC;            // slot4: xk, later g
    float* xv   = xk + TC;            // slot5
    float* xw   = xv + TC;            // slot6
    float* xg   = xw + TC;            // slot7
    float* k0   = xg + TC;            // slot8: [T,512]
    float* v0   = k0 + (size_t)T_DIM * 512;  // slot9: [T,512]
    // aliases
    float* dec = sx;
    float* r   = xxx;
    float* tw  = mtl;
    float* y0  = xr;
    float* g   = xk;

    dim3 blk(256);
    int nElem4 = T_DIM * C_DIM / 4;

    // 1. prep
    prep_kernel<<<dim3((nElem4 + 255) / 256), blk, 0, stream>>>(x, state, ns, tmx, sx, xxx);
    // 2. mtl = tanh(xxx @ W1)   [T,160]
    gemm_f32<1><<<dim3(3, T_DIM / 64), blk, 0, stream>>>(xxx, W1, nullptr, mtl, T_DIM, 160, C_DIM);
    // 3. combine -> xr..xg
    maa_combine<<<dim3(T_DIM), blk, 0, stream>>>(x, sx, mtl, W2, tmr, tmk, tmv, tmw, tmg,
                                                 xr, xk, xv, xw, xg);
    // 4. projections
    gemm_f32<0><<<dim3(32, 32), blk, 0, stream>>>(xr, Wq, nullptr, r, T_DIM, 2048, C_DIM);
    gemm_f32<0><<<dim3(8, 32), blk, 0, stream>>>(xk, Wk, nullptr, k0, T_DIM, 512, C_DIM);
    gemm_f32<0><<<dim3(8, 32), blk, 0, stream>>>(xv, Wv, nullptr, v0, T_DIM, 512, C_DIM);
    gemm_f32<1><<<dim3(1, 32), blk, 0, stream>>>(xw, Wd1, nullptr, tw, T_DIM, 64, C_DIM);
    gemm_f32<3><<<dim3(32, 32), blk, 0, stream>>>(tw, Wd2, tdec, dec, T_DIM, 2048, 64);
    gemm_f32<2><<<dim3(32, 32), blk, 0, stream>>>(xg, Wg, nullptr, g, T_DIM, 2048, C_DIM);
    // 5. scan
    scan_kernel<<<dim3(NH), dim3(64), 0, stream>>>(r, k0, v0, dec, state, ns, y0, outstate);
    // 6. y = y0*g ; out = y @ Wo ; state row 0
    mulg_kernel<<<dim3((nElem4 + 255) / 256), blk, 0, stream>>>(y0, g);
    gemm_f32<0><<<dim3(32, 32), blk, 0, stream>>>(y0, Wo, nullptr, out, T_DIM, 2048, C_DIM);
    state0_kernel<<<dim3(8), blk, 0, stream>>>(x, len, outstate);
}

// Round 2
// 2064.822 us; speedup vs baseline: 2.2267x; 2.2267x over previous
//
#include <hip/hip_runtime.h>
#include <cmath>

#define T_DIM 2048
#define C_DIM 2048
#define NH    32
#define SS    64
#define NC    32    // chunks
#define CL    64    // chunk length

// ---------------------------------------------------------------------------
// Kernel 1: token-shift prep.  sx = (ns? 0 : prev_token) - x ; xxx = x + sx*tmx
// ---------------------------------------------------------------------------
__global__ __launch_bounds__(256)
void prep_kernel(const float* __restrict__ x, const float* __restrict__ state,
                 const unsigned char* __restrict__ ns,
                 const float* __restrict__ tmx,
                 float* __restrict__ sx, float* __restrict__ xxx) {
    int i4 = blockIdx.x * 256 + threadIdx.x;          // over T*C/4
    if (i4 >= T_DIM * C_DIM / 4) return;
    int idx = i4 * 4;
    int t = idx >> 11;
    int c = idx & 2047;
    float4 xv = *(const float4*)(x + idx);
    float4 prev;
    if (ns[t]) {
        prev = make_float4(0.f, 0.f, 0.f, 0.f);
    } else if (t == 0) {
        prev = *(const float4*)(state + c);
    } else {
        prev = *(const float4*)(x + idx - C_DIM);
    }
    float4 tm = *(const float4*)(tmx + c);
    float4 s4, xx4;
    s4.x = prev.x - xv.x;  s4.y = prev.y - xv.y;
    s4.z = prev.z - xv.z;  s4.w = prev.w - xv.w;
    xx4.x = xv.x + s4.x * tm.x;  xx4.y = xv.y + s4.y * tm.y;
    xx4.z = xv.z + s4.z * tm.z;  xx4.w = xv.w + s4.w * tm.w;
    *(float4*)(sx + idx)  = s4;
    *(float4*)(xxx + idx) = xx4;
}

// ---------------------------------------------------------------------------
// Generic fp32 tiled GEMM: C[M,N] = epi(A[M,K] @ B[K,N]).
// BM=BN=64, BK=16, 256 threads, 4x4 micro-tile.
// EPI: 0 none, 1 tanh, 2 sigmoid, 3 +bias[col]
// ---------------------------------------------------------------------------
template<int EPI>
__global__ __launch_bounds__(256)
void gemm_f32(const float* __restrict__ A, const float* __restrict__ B,
              const float* __restrict__ bias, float* __restrict__ C,
              int M, int N, int K) {
    __shared__ float As[16][65];   // [k][m], padded
    __shared__ float Bs[16][64];   // [k][n]
    int tid = threadIdx.x;
    int tx = tid & 15;             // output col group
    int ty = tid >> 4;             // output row group
    int m0 = blockIdx.y * 64;
    int n0 = blockIdx.x * 64;
    int arow = tid >> 2;           // 0..63
    int acol = (tid & 3) << 2;     // 0,4,8,12
    int brow = tid >> 4;           // 0..15
    int bcol = (tid & 15) << 2;    // 0..60

    float acc[4][4] = {};

    for (int k0 = 0; k0 < K; k0 += 16) {
        float4 a4 = *(const float4*)(A + (size_t)(m0 + arow) * K + k0 + acol);
        As[acol + 0][arow] = a4.x;
        As[acol + 1][arow] = a4.y;
        As[acol + 2][arow] = a4.z;
        As[acol + 3][arow] = a4.w;
        float4 b4 = make_float4(0.f, 0.f, 0.f, 0.f);
        if (n0 + bcol < N)
            b4 = *(const float4*)(B + (size_t)(k0 + brow) * N + n0 + bcol);
        *(float4*)&Bs[brow][bcol] = b4;
        __syncthreads();
        #pragma unroll
        for (int kk = 0; kk < 16; ++kk) {
            float a[4], b[4];
            #pragma unroll
            for (int i = 0; i < 4; ++i) a[i] = As[kk][ty * 4 + i];
            #pragma unroll
            for (int j = 0; j < 4; ++j) b[j] = Bs[kk][tx * 4 + j];
            #pragma unroll
            for (int i = 0; i < 4; ++i)
                #pragma unroll
                for (int j = 0; j < 4; ++j)
                    acc[i][j] = fmaf(a[i], b[j], acc[i][j]);
        }
        __syncthreads();
    }

    #pragma unroll
    for (int i = 0; i < 4; ++i) {
        int row = m0 + ty * 4 + i;
        #pragma unroll
        for (int j = 0; j < 4; ++j) {
            int col = n0 + tx * 4 + j;
            if (col < N) {
                float v = acc[i][j];
                if (EPI == 1) v = tanhf(v);
                else if (EPI == 2) v = 1.f / (1.f + __expf(-v));
                else if (EPI == 3) v = v + bias[col];
                C[(size_t)row * N + col] = v;
            }
        }
    }
}

// ---------------------------------------------------------------------------
// Kernel 3: LoRA combine.
// ---------------------------------------------------------------------------
__global__ __launch_bounds__(256)
void maa_combine(const float* __restrict__ x, const float* __restrict__ sx,
                 const float* __restrict__ mtl, const float* __restrict__ W2,
                 const float* __restrict__ tmr, const float* __restrict__ tmk,
                 const float* __restrict__ tmv, const float* __restrict__ tmw,
                 const float* __restrict__ tmg,
                 float* __restrict__ xr, float* __restrict__ xk,
                 float* __restrict__ xv, float* __restrict__ xw,
                 float* __restrict__ xg) {
    int t = blockIdx.x;
    __shared__ float ml[160];
    if (threadIdx.x < 160) ml[threadIdx.x] = mtl[t * 160 + threadIdx.x];
    __syncthreads();
    for (int c = threadIdx.x; c < C_DIM; c += 256) {
        float a0 = 0.f, a1 = 0.f, a2 = 0.f, a3 = 0.f, a4 = 0.f;
        #pragma unroll 8
        for (int l = 0; l < 32; ++l) {
            a0 = fmaf(ml[l],       W2[(size_t)(l)       * C_DIM + c], a0);
            a1 = fmaf(ml[32 + l],  W2[(size_t)(32 + l)  * C_DIM + c], a1);
            a2 = fmaf(ml[64 + l],  W2[(size_t)(64 + l)  * C_DIM + c], a2);
            a3 = fmaf(ml[96 + l],  W2[(size_t)(96 + l)  * C_DIM + c], a3);
            a4 = fmaf(ml[128 + l], W2[(size_t)(128 + l) * C_DIM + c], a4);
        }
        size_t idx = (size_t)t * C_DIM + c;
        float xval = x[idx], sxv = sx[idx];
        xr[idx] = xval + sxv * (tmr[c] + a0);
        xk[idx] = xval + sxv * (tmk[c] + a1);
        xv[idx] = xval + sxv * (tmv[c] + a2);
        xw[idx] = xval + sxv * (tmw[c] + a3);
        xg[idx] = xval + sxv * (tmg[c] + a4);
    }
}

// ---------------------------------------------------------------------------
// Chunked scan pass 1: per (head, chunk) compute
//   P[k]    = prod_{t in chunk} ew'_t[k]           (ew' = ns? 0 : ew)
//   U[k][v] = chunk-local scan result from zero init
// Grid (NH, NC) x 64 threads. Lane = v column; lane index doubles as k for P.
// ---------------------------------------------------------------------------
__global__ __launch_bounds__(64)
void scan_pass1(const float* __restrict__ k0, const float* __restrict__ v0,
                const float* __restrict__ dec, const unsigned char* __restrict__ ns,
                float* __restrict__ U, float* __restrict__ P) {
    int h = blockIdx.x, c = blockIdx.y, v = threadIdx.x;
    int hk = h >> 2;
    float u[64];
    #pragma unroll
    for (int k = 0; k < 64; ++k) u[k] = 0.f;
    float pk = 1.f;
    __shared__ float ew_s[64], kk_s[64];
    for (int i = 0; i < CL; ++i) {
        int t = c * CL + i;
        float dv = dec[(size_t)t * 2048 + h * 64 + v];
        float lw = fmaxf(-__expf(dv), -5.f);
        float ew = __expf(lw);
        float ewp = ns[t] ? 0.f : ew;
        ew_s[v] = ewp;
        kk_s[v] = k0[(size_t)t * 512 + hk * 64 + v] * (1.f - ew);
        __syncthreads();
        float vv = v0[(size_t)t * 512 + hk * 64 + v];
        pk *= ewp;
        #pragma unroll
        for (int k = 0; k < 64; ++k)
            u[k] = fmaf(u[k], ew_s[k], kk_s[k] * vv);
        __syncthreads();
    }
    size_t base = ((size_t)h * NC + c) * 4096;
    #pragma unroll
    for (int k = 0; k < 64; ++k) U[base + k * 64 + v] = u[k];
    P[((size_t)h * NC + c) * 64 + v] = pk;
}

// ---------------------------------------------------------------------------
// Chunked scan pass 2: sequential combine over chunks.
//   store S_start(c); S <- P_c * S + U_c.   Also writes final state.
// Grid NH x 64 threads.
// ---------------------------------------------------------------------------
__global__ __launch_bounds__(64)
void scan_pass2(const float* __restrict__ U, const float* __restrict__ P,
                const float* __restrict__ state,
                float* __restrict__ Sstarts, float* __restrict__ outstate) {
    int h = blockIdx.x, v = threadIdx.x;
    float s[64];
    #pragma unroll
    for (int k = 0; k < 64; ++k) s[k] = state[C_DIM + h * 4096 + k * 64 + v];
    __shared__ float p_s[64];
    for (int c = 0; c < NC; ++c) {
        size_t base = ((size_t)h * NC + c) * 4096;
        #pragma unroll
        for (int k = 0; k < 64; ++k) Sstarts[base + k * 64 + v] = s[k];
        p_s[v] = P[((size_t)h * NC + c) * 64 + v];
        __syncthreads();
        #pragma unroll
        for (int k = 0; k < 64; ++k)
            s[k] = fmaf(s[k], p_s[k], U[base + k * 64 + v]);
        __syncthreads();
    }
    #pragma unroll
    for (int k = 0; k < 64; ++k)
        outstate[C_DIM + h * 4096 + k * 64 + v] = s[k];
}

// ---------------------------------------------------------------------------
// Chunked scan pass 3: replay chunk from its start state, emit outputs.
// Grid (NH, NC) x 64 threads.
// ---------------------------------------------------------------------------
__global__ __launch_bounds__(64)
void scan_pass3(const float* __restrict__ r, const float* __restrict__ k0,
                const float* __restrict__ v0, const float* __restrict__ dec,
                const unsigned char* __restrict__ ns,
                const float* __restrict__ Sstarts, float* __restrict__ y0) {
    int h = blockIdx.x, c = blockIdx.y, v = threadIdx.x;
    int hk = h >> 2;
    float s[64];
    size_t base = ((size_t)h * NC + c) * 4096;
    #pragma unroll
    for (int k = 0; k < 64; ++k) s[k] = Sstarts[base + k * 64 + v];
    __shared__ float r_s[64], ew_s[64], kk_s[64];
    for (int i = 0; i < CL; ++i) {
        int t = c * CL + i;
        float dv = dec[(size_t)t * 2048 + h * 64 + v];
        float lw = fmaxf(-__expf(dv), -5.f);
        float ew = __expf(lw);
        ew_s[v] = ns[t] ? 0.f : ew;
        kk_s[v] = k0[(size_t)t * 512 + hk * 64 + v] * (1.f - ew);
        r_s[v]  = r[(size_t)t * 2048 + h * 64 + v];
        __syncthreads();
        float vv = v0[(size_t)t * 512 + hk * 64 + v];
        float o = 0.f;
        #pragma unroll
        for (int k = 0; k < 64; ++k) {
            float sk = fmaf(s[k], ew_s[k], kk_s[k] * vv);
            s[k] = sk;
            o = fmaf(r_s[k], sk, o);
        }
        y0[(size_t)t * 2048 + h * 64 + v] = o;
        __syncthreads();
    }
}

// ---------------------------------------------------------------------------
// y0 *= g (in place, float4)
// ---------------------------------------------------------------------------
__global__ __launch_bounds__(256)
void mulg_kernel(float* __restrict__ y0, const float* __restrict__ g) {
    int i4 = blockIdx.x * 256 + threadIdx.x;
    if (i4 >= T_DIM * C_DIM / 4) return;
    float4 a = *(float4*)(y0 + i4 * 4);
    float4 b = *(const float4*)(g + i4 * 4);
    a.x *= b.x; a.y *= b.y; a.z *= b.z; a.w *= b.w;
    *(float4*)(y0 + i4 * 4) = a;
}

// ---------------------------------------------------------------------------
// new_state row 0 = x[length-1]
// ---------------------------------------------------------------------------
__global__ __launch_bounds__(256)
void state0_kernel(const float* __restrict__ x, const int* __restrict__ len,
                   float* __restrict__ outstate) {
    int c = blockIdx.x * 256 + threadIdx.x;
    if (c < C_DIM)
        outstate[c] = x[(size_t)(len[0] - 1) * C_DIM + c];
}

// ---------------------------------------------------------------------------
extern "C" void kernel_launch(void* const* d_in, const int* in_sizes, int n_in,
                              void* d_out, int out_size, void* d_ws, size_t ws_size,
                              hipStream_t stream) {
    const float* x     = (const float*)d_in[0];
    const float* state = (const float*)d_in[1];
    const unsigned char* ns = (const unsigned char*)d_in[2];
    const int*   len   = (const int*)d_in[3];
    const float* tmx   = (const float*)d_in[4];
    const float* tmr   = (const float*)d_in[5];
    const float* tmk   = (const float*)d_in[6];
    const float* tmv   = (const float*)d_in[7];
    const float* tmw   = (const float*)d_in[8];
    const float* tmg   = (const float*)d_in[9];
    const float* W1    = (const float*)d_in[10];   // [C,160]
    const float* W2    = (const float*)d_in[11];   // [5,32,C]
    const float* tdec  = (const float*)d_in[12];   // [C]
    const float* Wd1   = (const float*)d_in[13];   // [C,64]
    const float* Wd2   = (const float*)d_in[14];   // [64,C]
    const float* Wq    = (const float*)d_in[15];
    const float* Wk    = (const float*)d_in[16];
    const float* Wv    = (const float*)d_in[17];
    const float* Wg    = (const float*)d_in[18];
    const float* Wo    = (const float*)d_in[19];

    float* out = (float*)d_out;            // [T*C] y, then [65*C] new_state
    float* outstate = out + (size_t)T_DIM * C_DIM;

    // workspace layout (floats), with aliasing:
    float* ws = (float*)d_ws;
    const size_t TC = (size_t)T_DIM * C_DIM;      // 4,194,304
    float* sx   = ws;                 // slot0: sx, later dec
    float* xxx  = ws + TC;            // slot1: xxx, later r
    float* mtl  = ws + 2 * TC;        // slot2: [T,160], later tw [T,64]
    float* xr   = ws + 2 * TC + 327680;   // slot3: xr, later y0
    float* xk   = xr + TC;            // slot4: xk, later g
    float* xv   = xk + TC;            // slot5: xv, later U   [H,NC,64,64]
    float* xw   = xv + TC;            // slot6: xw, later P   [H,NC,64]
    float* xg   = xw + TC;            // slot7: xg, later Sstarts [H,NC,64,64]
    float* k0   = xg + TC;            // slot8: [T,512]
    float* v0   = k0 + (size_t)T_DIM * 512;  // slot9: [T,512]
    // aliases
    float* dec = sx;
    float* r   = xxx;
    float* tw  = mtl;
    float* y0  = xr;
    float* g   = xk;
    float* U       = xv;
    float* P       = xw;
    float* Sstarts = xg;

    dim3 blk(256);
    int nElem4 = T_DIM * C_DIM / 4;

    // 1. prep
    prep_kernel<<<dim3((nElem4 + 255) / 256), blk, 0, stream>>>(x, state, ns, tmx, sx, xxx);
    // 2. mtl = tanh(xxx @ W1)   [T,160]
    gemm_f32<1><<<dim3(3, T_DIM / 64), blk, 0, stream>>>(xxx, W1, nullptr, mtl, T_DIM, 160, C_DIM);
    // 3. combine -> xr..xg
    maa_combine<<<dim3(T_DIM), blk, 0, stream>>>(x, sx, mtl, W2, tmr, tmk, tmv, tmw, tmg,
                                                 xr, xk, xv, xw, xg);
    // 4. projections
    gemm_f32<0><<<dim3(32, 32), blk, 0, stream>>>(xr, Wq, nullptr, r, T_DIM, 2048, C_DIM);
    gemm_f32<1><<<dim3(1, 32), blk, 0, stream>>>(xw, Wd1, nullptr, tw, T_DIM, 64, C_DIM);
    gemm_f32<0><<<dim3(8, 32), blk, 0, stream>>>(xk, Wk, nullptr, k0, T_DIM, 512, C_DIM);
    gemm_f32<0><<<dim3(8, 32), blk, 0, stream>>>(xv, Wv, nullptr, v0, T_DIM, 512, C_DIM);
    gemm_f32<3><<<dim3(32, 32), blk, 0, stream>>>(tw, Wd2, tdec, dec, T_DIM, 2048, 64);
    gemm_f32<2><<<dim3(32, 32), blk, 0, stream>>>(xg, Wg, nullptr, g, T_DIM, 2048, C_DIM);
    // 5. chunked scan
    scan_pass1<<<dim3(NH, NC), dim3(64), 0, stream>>>(k0, v0, dec, ns, U, P);
    scan_pass2<<<dim3(NH), dim3(64), 0, stream>>>(U, P, state, Sstarts, outstate);
    scan_pass3<<<dim3(NH, NC), dim3(64), 0, stream>>>(r, k0, v0, dec, ns, Sstarts, y0);
    // 6. y = y0*g ; out = y @ Wo ; state row 0
    mulg_kernel<<<dim3((nElem4 + 255) / 256), blk, 0, stream>>>(y0, g);
    gemm_f32<0><<<dim3(32, 32), blk, 0, stream>>>(y0, Wo, nullptr, out, T_DIM, 2048, C_DIM);
    state0_kernel<<<dim3(8), blk, 0, stream>>>(x, len, outstate);
}

// Round 3
// 974.107 us; speedup vs baseline: 4.7199x; 2.1197x over previous
//
#include <hip/hip_runtime.h>
#include <hip/hip_bf16.h>
#include <cmath>

#define T_DIM 2048
#define C_DIM 2048
#define NH    32
#define SS    64
#define NC    32    // chunks
#define CL    64    // chunk length

typedef unsigned short ushort_t;
typedef __attribute__((ext_vector_type(8))) short bf16x8;
typedef __attribute__((ext_vector_type(4))) float f32x4;

__device__ __forceinline__ ushort_t f2bf(float v) {
    union { __hip_bfloat16 b; ushort_t u; } cv;
    cv.b = __float2bfloat16(v);
    return cv.u;
}

__device__ __forceinline__ void gload_lds16(const void* g, void* l) {
    __builtin_amdgcn_global_load_lds((const __attribute__((address_space(1))) void*)g,
                                     (__attribute__((address_space(3))) void*)l,
                                     16, 0, 0);
}

// ---------------------------------------------------------------------------
// Weight cast + transpose: W[K,N] fp32 -> WT[NT,K] bf16 (rows >= N zero-padded)
// ---------------------------------------------------------------------------
__global__ __launch_bounds__(256)
void castT_kernel(const float* __restrict__ W, ushort_t* __restrict__ WT,
                  int K, int N) {
    __shared__ float t[32][33];
    int n0 = blockIdx.x * 32, k0 = blockIdx.y * 32;
    int tx = threadIdx.x & 31, ty = threadIdx.x >> 5;   // 32 x 8
    #pragma unroll
    for (int i = 0; i < 4; ++i) {
        int k = ty + i * 8;
        float v = 0.f;
        if (n0 + tx < N) v = W[(size_t)(k0 + k) * N + n0 + tx];
        t[k][tx] = v;
    }
    __syncthreads();
    #pragma unroll
    for (int i = 0; i < 4; ++i) {
        int n = ty + i * 8;
        WT[(size_t)(n0 + n) * K + k0 + tx] = f2bf(t[tx][n]);
    }
}

// ---------------------------------------------------------------------------
// token-shift prep: sx = (ns?0:prev) - x (fp32) ; xxxb = bf16(x + sx*tmx)
// ---------------------------------------------------------------------------
__global__ __launch_bounds__(256)
void prep_kernel(const float* __restrict__ x, const float* __restrict__ state,
                 const unsigned char* __restrict__ ns,
                 const float* __restrict__ tmx,
                 float* __restrict__ sx, ushort_t* __restrict__ xxxb) {
    int i4 = blockIdx.x * 256 + threadIdx.x;
    if (i4 >= T_DIM * C_DIM / 4) return;
    int idx = i4 * 4;
    int t = idx >> 11;
    int c = idx & 2047;
    float4 xv = *(const float4*)(x + idx);
    float4 prev;
    if (ns[t]) prev = make_float4(0.f, 0.f, 0.f, 0.f);
    else if (t == 0) prev = *(const float4*)(state + c);
    else prev = *(const float4*)(x + idx - C_DIM);
    float4 tm = *(const float4*)(tmx + c);
    float4 s4;
    s4.x = prev.x - xv.x;  s4.y = prev.y - xv.y;
    s4.z = prev.z - xv.z;  s4.w = prev.w - xv.w;
    *(float4*)(sx + idx) = s4;
    ushort4 xb;
    xb.x = f2bf(xv.x + s4.x * tm.x);
    xb.y = f2bf(xv.y + s4.y * tm.y);
    xb.z = f2bf(xv.z + s4.z * tm.z);
    xb.w = f2bf(xv.w + s4.w * tm.w);
    *(ushort4*)(xxxb + idx) = xb;
}

// ---------------------------------------------------------------------------
// bf16 MFMA GEMM: C[M,N] = epi(A[M,K(lda)] @ BT[N,K]^T)
// BM=BN=128, BK=32, 256 threads (4 waves, 2x2 of 64x64), 16x16x32 MFMA.
// XOR k-chunk swizzle kills LDS bank conflicts. M = grid.y*128.
// EPI: 0 none(f32) 1 tanh(f32) 2 sigmoid(f32) 3 +bias(f32) 4 tanh(bf16)
// ---------------------------------------------------------------------------
template<int EPI>
__global__ __launch_bounds__(256)
void gemm_mfma(const ushort_t* __restrict__ A, int lda,
               const ushort_t* __restrict__ BT,
               const float* __restrict__ bias,
               float* __restrict__ Cf, ushort_t* __restrict__ Cb,
               int ldc, int K) {
    __shared__ ushort_t As[128 * 32];
    __shared__ ushort_t Bs[128 * 32];
    int tid = threadIdx.x;
    int wave = tid >> 6, lane = tid & 63;
    int m0 = blockIdx.y * 128, n0 = blockIdx.x * 128;
    int wm = wave >> 1, wn = wave & 1;

    f32x4 acc[4][4] = {};

    int srow0 = wave * 16 + (lane >> 2);   // staging row within 64-row group
    int schunk = lane & 3;                 // 16B chunk slot 0..3

    for (int k0 = 0; k0 < K; k0 += 32) {
        #pragma unroll
        for (int j = 0; j < 2; ++j) {
            int row = j * 64 + srow0;
            int gch = schunk ^ (row & 3);  // swizzled global chunk
            gload_lds16(A + (size_t)(m0 + row) * lda + k0 + gch * 8,
                        As + row * 32 + schunk * 8);
            gload_lds16(BT + (size_t)(n0 + row) * K + k0 + gch * 8,
                        Bs + row * 32 + schunk * 8);
        }
        __syncthreads();

        int fr = lane & 15;
        int fc = lane >> 4;                // logical k-chunk 0..3
        bf16x8 af[4], bfr[4];
        #pragma unroll
        for (int mi = 0; mi < 4; ++mi) {
            int r = wm * 64 + mi * 16 + fr;
            af[mi] = *(const bf16x8*)(As + r * 32 + ((fc ^ (r & 3)) * 8));
        }
        #pragma unroll
        for (int ni = 0; ni < 4; ++ni) {
            int c = wn * 64 + ni * 16 + fr;
            bfr[ni] = *(const bf16x8*)(Bs + c * 32 + ((fc ^ (c & 3)) * 8));
        }
        #pragma unroll
        for (int mi = 0; mi < 4; ++mi)
            #pragma unroll
            for (int ni = 0; ni < 4; ++ni)
                acc[mi][ni] = __builtin_amdgcn_mfma_f32_16x16x32_bf16(
                    af[mi], bfr[ni], acc[mi][ni], 0, 0, 0);
        __syncthreads();
    }

    // epilogue: C/D layout col=lane&15, row=(lane>>4)*4+reg
    int colin = lane & 15;
    int rquad = lane >> 4;
    #pragma unroll
    for (int mi = 0; mi < 4; ++mi) {
        #pragma unroll
        for (int reg = 0; reg < 4; ++reg) {
            int row = m0 + wm * 64 + mi * 16 + rquad * 4 + reg;
            #pragma unroll
            for (int ni = 0; ni < 4; ++ni) {
                int col = n0 + wn * 64 + ni * 16 + colin;
                float v = acc[mi][ni][reg];
                if (EPI == 1) v = tanhf(v);
                else if (EPI == 2) v = 1.f / (1.f + __expf(-v));
                else if (EPI == 3) v += bias[col];
                else if (EPI == 4) v = tanhf(v);
                if (EPI == 4) Cb[(size_t)row * ldc + col] = f2bf(v);
                else          Cf[(size_t)row * ldc + col] = v;
            }
        }
    }
}

// ---------------------------------------------------------------------------
// LoRA combine -> bf16 branch inputs.  mtl has stride 256 (padded).
// ---------------------------------------------------------------------------
__global__ __launch_bounds__(256)
void maa_combine(const float* __restrict__ x, const float* __restrict__ sx,
                 const float* __restrict__ mtl, const float* __restrict__ W2,
                 const float* __restrict__ tmr, const float* __restrict__ tmk,
                 const float* __restrict__ tmv, const float* __restrict__ tmw,
                 const float* __restrict__ tmg,
                 ushort_t* __restrict__ xr, ushort_t* __restrict__ xk,
                 ushort_t* __restrict__ xv, ushort_t* __restrict__ xw,
                 ushort_t* __restrict__ xg) {
    int t = blockIdx.x;
    __shared__ float ml[160];
    if (threadIdx.x < 160) ml[threadIdx.x] = mtl[(size_t)t * 256 + threadIdx.x];
    __syncthreads();
    for (int c = threadIdx.x; c < C_DIM; c += 256) {
        float a0 = 0.f, a1 = 0.f, a2 = 0.f, a3 = 0.f, a4 = 0.f;
        #pragma unroll 8
        for (int l = 0; l < 32; ++l) {
            a0 = fmaf(ml[l],       W2[(size_t)(l)       * C_DIM + c], a0);
            a1 = fmaf(ml[32 + l],  W2[(size_t)(32 + l)  * C_DIM + c], a1);
            a2 = fmaf(ml[64 + l],  W2[(size_t)(64 + l)  * C_DIM + c], a2);
            a3 = fmaf(ml[96 + l],  W2[(size_t)(96 + l)  * C_DIM + c], a3);
            a4 = fmaf(ml[128 + l], W2[(size_t)(128 + l) * C_DIM + c], a4);
        }
        size_t idx = (size_t)t * C_DIM + c;
        float xval = x[idx], sxv = sx[idx];
        xr[idx] = f2bf(xval + sxv * (tmr[c] + a0));
        xk[idx] = f2bf(xval + sxv * (tmk[c] + a1));
        xv[idx] = f2bf(xval + sxv * (tmv[c] + a2));
        xw[idx] = f2bf(xval + sxv * (tmw[c] + a3));
        xg[idx] = f2bf(xval + sxv * (tmg[c] + a4));
    }
}

// ---------------------------------------------------------------------------
// Chunked scan pass 1: per (head, chunk): P[k]=prod ew', U = chunk-local scan.
// ---------------------------------------------------------------------------
__global__ __launch_bounds__(64)
void scan_pass1(const float* __restrict__ k0, const float* __restrict__ v0,
                const float* __restrict__ dec, const unsigned char* __restrict__ ns,
                float* __restrict__ U, float* __restrict__ P) {
    int h = blockIdx.x, c = blockIdx.y, v = threadIdx.x;
    int hk = h >> 2;
    float u[64];
    #pragma unroll
    for (int k = 0; k < 64; ++k) u[k] = 0.f;
    float pk = 1.f;
    __shared__ float ew_s[64], kk_s[64];
    for (int i = 0; i < CL; ++i) {
        int t = c * CL + i;
        float dv = dec[(size_t)t * 2048 + h * 64 + v];
        float lw = fmaxf(-__expf(dv), -5.f);
        float ew = __expf(lw);
        float ewp = ns[t] ? 0.f : ew;
        ew_s[v] = ewp;
        kk_s[v] = k0[(size_t)t * 512 + hk * 64 + v] * (1.f - ew);
        __syncthreads();
        float vv = v0[(size_t)t * 512 + hk * 64 + v];
        pk *= ewp;
        #pragma unroll
        for (int k = 0; k < 64; ++k)
            u[k] = fmaf(u[k], ew_s[k], kk_s[k] * vv);
        __syncthreads();
    }
    size_t base = ((size_t)h * NC + c) * 4096;
    #pragma unroll
    for (int k = 0; k < 64; ++k) U[base + k * 64 + v] = u[k];
    P[((size_t)h * NC + c) * 64 + v] = pk;
}

// ---------------------------------------------------------------------------
// Pass 2: sequential combine; U is replaced IN PLACE by chunk-start states.
// ---------------------------------------------------------------------------
__global__ __launch_bounds__(64)
void scan_pass2(float* U, const float* __restrict__ P,
                const float* __restrict__ state, float* __restrict__ outstate) {
    int h = blockIdx.x, v = threadIdx.x;
    float s[64];
    #pragma unroll
    for (int k = 0; k < 64; ++k) s[k] = state[C_DIM + h * 4096 + k * 64 + v];
    __shared__ float p_s[64];
    for (int c = 0; c < NC; ++c) {
        size_t base = ((size_t)h * NC + c) * 4096;
        p_s[v] = P[((size_t)h * NC + c) * 64 + v];
        __syncthreads();
        #pragma unroll
        for (int k = 0; k < 64; ++k) {
            float start = s[k];
            s[k] = fmaf(s[k], p_s[k], U[base + k * 64 + v]);
            U[base + k * 64 + v] = start;
        }
        __syncthreads();
    }
    #pragma unroll
    for (int k = 0; k < 64; ++k)
        outstate[C_DIM + h * 4096 + k * 64 + v] = s[k];
}

// ---------------------------------------------------------------------------
// Pass 3: replay chunk from start state (now stored in U), emit y0.
// ---------------------------------------------------------------------------
__global__ __launch_bounds__(64)
void scan_pass3(const float* __restrict__ r, const float* __restrict__ k0,
                const float* __restrict__ v0, const float* __restrict__ dec,
                const unsigned char* __restrict__ ns,
                const float* __restrict__ Sstarts, float* __restrict__ y0) {
    int h = blockIdx.x, c = blockIdx.y, v = threadIdx.x;
    int hk = h >> 2;
    float s[64];
    size_t base = ((size_t)h * NC + c) * 4096;
    #pragma unroll
    for (int k = 0; k < 64; ++k) s[k] = Sstarts[base + k * 64 + v];
    __shared__ float r_s[64], ew_s[64], kk_s[64];
    for (int i = 0; i < CL; ++i) {
        int t = c * CL + i;
        float dv = dec[(size_t)t * 2048 + h * 64 + v];
        float lw = fmaxf(-__expf(dv), -5.f);
        float ew = __expf(lw);
        ew_s[v] = ns[t] ? 0.f : ew;
        kk_s[v] = k0[(size_t)t * 512 + hk * 64 + v] * (1.f - ew);
        r_s[v]  = r[(size_t)t * 2048 + h * 64 + v];
        __syncthreads();
        float vv = v0[(size_t)t * 512 + hk * 64 + v];
        float o = 0.f;
        #pragma unroll
        for (int k = 0; k < 64; ++k) {
            float sk = fmaf(s[k], ew_s[k], kk_s[k] * vv);
            s[k] = sk;
            o = fmaf(r_s[k], sk, o);
        }
        y0[(size_t)t * 2048 + h * 64 + v] = o;
        __syncthreads();
    }
}

// ---------------------------------------------------------------------------
// y0b = bf16(y0 * g)
// ---------------------------------------------------------------------------
__global__ __launch_bounds__(256)
void mulg_kernel(const float* __restrict__ y0, const float* __restrict__ g,
                 ushort_t* __restrict__ y0b) {
    int i4 = blockIdx.x * 256 + threadIdx.x;
    if (i4 >= T_DIM * C_DIM / 4) return;
    float4 a = *(const float4*)(y0 + i4 * 4);
    float4 b = *(const float4*)(g + i4 * 4);
    ushort4 o;
    o.x = f2bf(a.x * b.x); o.y = f2bf(a.y * b.y);
    o.z = f2bf(a.z * b.z); o.w = f2bf(a.w * b.w);
    *(ushort4*)(y0b + i4 * 4) = o;
}

__global__ __launch_bounds__(256)
void state0_kernel(const float* __restrict__ x, const int* __restrict__ len,
                   float* __restrict__ outstate) {
    int c = blockIdx.x * 256 + threadIdx.x;
    if (c < C_DIM)
        outstate[c] = x[(size_t)(len[0] - 1) * C_DIM + c];
}

// ---------------------------------------------------------------------------
extern "C" void kernel_launch(void* const* d_in, const int* in_sizes, int n_in,
                              void* d_out, int out_size, void* d_ws, size_t ws_size,
                              hipStream_t stream) {
    const float* x     = (const float*)d_in[0];
    const float* state = (const float*)d_in[1];
    const unsigned char* ns = (const unsigned char*)d_in[2];
    const int*   len   = (const int*)d_in[3];
    const float* tmx   = (const float*)d_in[4];
    const float* tmr   = (const float*)d_in[5];
    const float* tmk   = (const float*)d_in[6];
    const float* tmv   = (const float*)d_in[7];
    const float* tmw   = (const float*)d_in[8];
    const float* tmg   = (const float*)d_in[9];
    const float* W1    = (const float*)d_in[10];   // [C,160]
    const float* W2    = (const float*)d_in[11];   // [5,32,C] fp32 (stays)
    const float* tdec  = (const float*)d_in[12];   // [C]
    const float* Wd1   = (const float*)d_in[13];   // [C,64]
    const float* Wd2   = (const float*)d_in[14];   // [64,C]
    const float* Wq    = (const float*)d_in[15];
    const float* Wk    = (const float*)d_in[16];
    const float* Wv    = (const float*)d_in[17];
    const float* Wg    = (const float*)d_in[18];
    const float* Wo    = (const float*)d_in[19];

    float* out = (float*)d_out;
    float* outstate = out + (size_t)T_DIM * C_DIM;

    // ---- workspace layout (byte offsets; 122 MB total, aliased) ----
    char* wsb = (char*)d_ws;
    const size_t MB = 1024 * 1024;
    float*    sx   = (float*)(wsb + 0);            // 16 MB; later dec
    ushort_t* xxxb = (ushort_t*)(wsb + 16 * MB);   // 8 MB; later y0b
    float*    mtl  = (float*)(wsb + 24 * MB);      // 2 MB region
    ushort_t* tw   = (ushort_t*)(wsb + 24 * MB);   //   tw [T,128] bf16 (after mtl dead)
    float*    P    = (float*)(wsb + 25 * MB);      //   P  [32*32*64] fp32
    ushort_t* xr   = (ushort_t*)(wsb + 26 * MB);   // 8 MB
    ushort_t* xk   = (ushort_t*)(wsb + 34 * MB);   // 8 MB
    ushort_t* xv   = (ushort_t*)(wsb + 42 * MB);   // 8 MB
    ushort_t* xw   = (ushort_t*)(wsb + 50 * MB);   // 8 MB
    ushort_t* xg   = (ushort_t*)(wsb + 58 * MB);   // 8 MB  (ends 66)
    float*    y0   = (float*)(wsb + 26 * MB);      // 16 MB over xr,xk
    float*    g    = (float*)(wsb + 42 * MB);      // 16 MB over xv,xw
    float*    r    = (float*)(wsb + 66 * MB);      // 16 MB
    float*    k0   = (float*)(wsb + 82 * MB);      // 4 MB
    float*    v0   = (float*)(wsb + 86 * MB);      // 4 MB
    ushort_t* WqT  = (ushort_t*)(wsb + 90 * MB);   // 8 MB
    ushort_t* WkT  = (ushort_t*)(wsb + 98 * MB);   // 2 MB
    ushort_t* WvT  = (ushort_t*)(wsb + 100 * MB);  // 2 MB
    ushort_t* W1T  = (ushort_t*)(wsb + 102 * MB);  // 1 MB  [256,2048]
    ushort_t* Wd1T = (ushort_t*)(wsb + 103 * MB);  // 0.5 MB [128,2048]
    ushort_t* Wd2T = (ushort_t*)(wsb + 103 * MB + 512 * 1024); // 0.25 MB [2048,64]
    ushort_t* WgT  = (ushort_t*)(wsb + 106 * MB);  // 8 MB
    ushort_t* WoT  = (ushort_t*)(wsb + 114 * MB);  // 8 MB (ends 122)
    float*    U    = (float*)(wsb + 90 * MB);      // 16 MB over WqT..pad (dead by pass1)
    float*    dec  = sx;
    ushort_t* y0b  = xxxb;

    dim3 blk(256);
    int nElem4 = T_DIM * C_DIM / 4;

    // ---- weight cast+transpose ----
    castT_kernel<<<dim3(8, 64), blk, 0, stream>>>(W1, W1T, 2048, 160);     // ->[256,2048]
    castT_kernel<<<dim3(4, 64), blk, 0, stream>>>(Wd1, Wd1T, 2048, 64);    // ->[128,2048]
    castT_kernel<<<dim3(64, 2), blk, 0, stream>>>(Wd2, Wd2T, 64, 2048);    // ->[2048,64]
    castT_kernel<<<dim3(64, 64), blk, 0, stream>>>(Wq, WqT, 2048, 2048);
    castT_kernel<<<dim3(16, 64), blk, 0, stream>>>(Wk, WkT, 2048, 512);
    castT_kernel<<<dim3(16, 64), blk, 0, stream>>>(Wv, WvT, 2048, 512);
    castT_kernel<<<dim3(64, 64), blk, 0, stream>>>(Wg, WgT, 2048, 2048);
    castT_kernel<<<dim3(64, 64), blk, 0, stream>>>(Wo, WoT, 2048, 2048);

    // ---- prep / LoRA ----
    prep_kernel<<<dim3((nElem4 + 255) / 256), blk, 0, stream>>>(x, state, ns, tmx, sx, xxxb);
    gemm_mfma<1><<<dim3(2, 16), blk, 0, stream>>>(xxxb, 2048, W1T, nullptr, mtl, nullptr, 256, 2048);
    maa_combine<<<dim3(T_DIM), blk, 0, stream>>>(x, sx, mtl, W2, tmr, tmk, tmv, tmw, tmg,
                                                 xr, xk, xv, xw, xg);
    // ---- projections (order matters for aliasing: tw before g; k/v before g; r before pass3) ----
    gemm_mfma<4><<<dim3(1, 16), blk, 0, stream>>>(xw, 2048, Wd1T, nullptr, nullptr, tw, 128, 2048);
    gemm_mfma<0><<<dim3(4, 16), blk, 0, stream>>>(xk, 2048, WkT, nullptr, k0, nullptr, 512, 2048);
    gemm_mfma<0><<<dim3(4, 16), blk, 0, stream>>>(xv, 2048, WvT, nullptr, v0, nullptr, 512, 2048);
    gemm_mfma<0><<<dim3(16, 16), blk, 0, stream>>>(xr, 2048, WqT, nullptr, r, nullptr, 2048, 2048);
    gemm_mfma<3><<<dim3(16, 16), blk, 0, stream>>>(tw, 128, Wd2T, tdec, dec, nullptr, 2048, 64);
    gemm_mfma<2><<<dim3(16, 16), blk, 0, stream>>>(xg, 2048, WgT, nullptr, g, nullptr, 2048, 2048);
    // ---- chunked scan ----
    scan_pass1<<<dim3(NH, NC), dim3(64), 0, stream>>>(k0, v0, dec, ns, U, P);
    scan_pass2<<<dim3(NH), dim3(64), 0, stream>>>(U, P, state, outstate);
    scan_pass3<<<dim3(NH, NC), dim3(64), 0, stream>>>(r, k0, v0, dec, ns, U, y0);
    // ---- output ----
    mulg_kernel<<<dim3((nElem4 + 255) / 256), blk, 0, stream>>>(y0, g, y0b);
    gemm_mfma<0><<<dim3(16, 16), blk, 0, stream>>>(y0b, 2048, WoT, nullptr, out, nullptr, 2048, 2048);
    state0_kernel<<<dim3(8), blk, 0, stream>>>(x, len, outstate);
}

// Round 4
// 804.662 us; speedup vs baseline: 5.7139x; 1.2106x over previous
//
#include <hip/hip_runtime.h>
#include <hip/hip_bf16.h>
#include <cmath>

#define T_DIM 2048
#define C_DIM 2048
#define NH    32
#define SS    64
#define NC    32    // chunks
#define CL    64    // chunk length

typedef unsigned short ushort_t;
typedef __attribute__((ext_vector_type(8))) short bf16x8;
typedef __attribute__((ext_vector_type(4))) float f32x4;

__device__ __forceinline__ ushort_t f2bf(float v) {
    union { __hip_bfloat16 b; ushort_t u; } cv;
    cv.b = __float2bfloat16(v);
    return cv.u;
}

__device__ __forceinline__ void gload_lds16(const void* g, void* l) {
    __builtin_amdgcn_global_load_lds((const __attribute__((address_space(1))) void*)g,
                                     (__attribute__((address_space(3))) void*)l,
                                     16, 0, 0);
}

// ---------------------------------------------------------------------------
// Weight cast + transpose: W[K,N] fp32 -> WT[NT,K] bf16 (rows >= N zero-padded)
// ---------------------------------------------------------------------------
__global__ __launch_bounds__(256)
void castT_kernel(const float* __restrict__ W, ushort_t* __restrict__ WT,
                  int K, int N) {
    __shared__ float t[32][33];
    int n0 = blockIdx.x * 32, k0 = blockIdx.y * 32;
    int tx = threadIdx.x & 31, ty = threadIdx.x >> 5;   // 32 x 8
    #pragma unroll
    for (int i = 0; i < 4; ++i) {
        int k = ty + i * 8;
        float v = 0.f;
        if (n0 + tx < N) v = W[(size_t)(k0 + k) * N + n0 + tx];
        t[k][tx] = v;
    }
    __syncthreads();
    #pragma unroll
    for (int i = 0; i < 4; ++i) {
        int n = ty + i * 8;
        WT[(size_t)(n0 + n) * K + k0 + tx] = f2bf(t[tx][n]);
    }
}

// ---------------------------------------------------------------------------
// token-shift prep: sx = (ns?0:prev) - x (fp32) ; xxxb = bf16(x + sx*tmx)
// ---------------------------------------------------------------------------
__global__ __launch_bounds__(256)
void prep_kernel(const float* __restrict__ x, const float* __restrict__ state,
                 const unsigned char* __restrict__ ns,
                 const float* __restrict__ tmx,
                 float* __restrict__ sx, ushort_t* __restrict__ xxxb) {
    int i4 = blockIdx.x * 256 + threadIdx.x;
    if (i4 >= T_DIM * C_DIM / 4) return;
    int idx = i4 * 4;
    int t = idx >> 11;
    int c = idx & 2047;
    float4 xv = *(const float4*)(x + idx);
    float4 prev;
    if (ns[t]) prev = make_float4(0.f, 0.f, 0.f, 0.f);
    else if (t == 0) prev = *(const float4*)(state + c);
    else prev = *(const float4*)(x + idx - C_DIM);
    float4 tm = *(const float4*)(tmx + c);
    float4 s4;
    s4.x = prev.x - xv.x;  s4.y = prev.y - xv.y;
    s4.z = prev.z - xv.z;  s4.w = prev.w - xv.w;
    *(float4*)(sx + idx) = s4;
    ushort4 xb;
    xb.x = f2bf(xv.x + s4.x * tm.x);
    xb.y = f2bf(xv.y + s4.y * tm.y);
    xb.z = f2bf(xv.z + s4.z * tm.z);
    xb.w = f2bf(xv.w + s4.w * tm.w);
    *(ushort4*)(xxxb + idx) = xb;
}

// ---------------------------------------------------------------------------
// bf16 MFMA GEMM: C[M,N] = epi(A[M,K(lda)] @ BT[N,K]^T)
// BM=BN=128, BK=32, 256 threads (4 waves, 2x2 of 64x64), 16x16x32 MFMA.
// EPI: 0 none(f32) 1 tanh(f32) 2 sigmoid(f32) 3 +bias(f32) 4 tanh(bf16)
// ---------------------------------------------------------------------------
template<int EPI>
__global__ __launch_bounds__(256)
void gemm_mfma(const ushort_t* __restrict__ A, int lda,
               const ushort_t* __restrict__ BT,
               const float* __restrict__ bias,
               float* __restrict__ Cf, ushort_t* __restrict__ Cb,
               int ldc, int K) {
    __shared__ ushort_t As[128 * 32];
    __shared__ ushort_t Bs[128 * 32];
    int tid = threadIdx.x;
    int wave = tid >> 6, lane = tid & 63;
    int m0 = blockIdx.y * 128, n0 = blockIdx.x * 128;
    int wm = wave >> 1, wn = wave & 1;

    f32x4 acc[4][4] = {};

    int srow0 = wave * 16 + (lane >> 2);   // staging row within 64-row group
    int schunk = lane & 3;                 // 16B chunk slot 0..3

    for (int k0 = 0; k0 < K; k0 += 32) {
        #pragma unroll
        for (int j = 0; j < 2; ++j) {
            int row = j * 64 + srow0;
            int gch = schunk ^ (row & 3);  // swizzled global chunk
            gload_lds16(A + (size_t)(m0 + row) * lda + k0 + gch * 8,
                        As + row * 32 + schunk * 8);
            gload_lds16(BT + (size_t)(n0 + row) * K + k0 + gch * 8,
                        Bs + row * 32 + schunk * 8);
        }
        __syncthreads();

        int fr = lane & 15;
        int fc = lane >> 4;                // logical k-chunk 0..3
        bf16x8 af[4], bfr[4];
        #pragma unroll
        for (int mi = 0; mi < 4; ++mi) {
            int r = wm * 64 + mi * 16 + fr;
            af[mi] = *(const bf16x8*)(As + r * 32 + ((fc ^ (r & 3)) * 8));
        }
        #pragma unroll
        for (int ni = 0; ni < 4; ++ni) {
            int c = wn * 64 + ni * 16 + fr;
            bfr[ni] = *(const bf16x8*)(Bs + c * 32 + ((fc ^ (c & 3)) * 8));
        }
        #pragma unroll
        for (int mi = 0; mi < 4; ++mi)
            #pragma unroll
            for (int ni = 0; ni < 4; ++ni)
                acc[mi][ni] = __builtin_amdgcn_mfma_f32_16x16x32_bf16(
                    af[mi], bfr[ni], acc[mi][ni], 0, 0, 0);
        __syncthreads();
    }

    // epilogue: C/D layout col=lane&15, row=(lane>>4)*4+reg
    int colin = lane & 15;
    int rquad = lane >> 4;
    #pragma unroll
    for (int mi = 0; mi < 4; ++mi) {
        #pragma unroll
        for (int reg = 0; reg < 4; ++reg) {
            int row = m0 + wm * 64 + mi * 16 + rquad * 4 + reg;
            #pragma unroll
            for (int ni = 0; ni < 4; ++ni) {
                int col = n0 + wn * 64 + ni * 16 + colin;
                float v = acc[mi][ni][reg];
                if (EPI == 1) v = tanhf(v);
                else if (EPI == 2) v = 1.f / (1.f + __expf(-v));
                else if (EPI == 3) v += bias[col];
                else if (EPI == 4) v = tanhf(v);
                if (EPI == 4) Cb[(size_t)row * ldc + col] = f2bf(v);
                else          Cf[(size_t)row * ldc + col] = v;
            }
        }
    }
}

// ---------------------------------------------------------------------------
// LoRA combine -> bf16 branch inputs.  mtl has stride 256 (padded).
// ---------------------------------------------------------------------------
__global__ __launch_bounds__(256)
void maa_combine(const float* __restrict__ x, const float* __restrict__ sx,
                 const float* __restrict__ mtl, const float* __restrict__ W2,
                 const float* __restrict__ tmr, const float* __restrict__ tmk,
                 const float* __restrict__ tmv, const float* __restrict__ tmw,
                 const float* __restrict__ tmg,
                 ushort_t* __restrict__ xr, ushort_t* __restrict__ xk,
                 ushort_t* __restrict__ xv, ushort_t* __restrict__ xw,
                 ushort_t* __restrict__ xg) {
    int t = blockIdx.x;
    __shared__ float ml[160];
    if (threadIdx.x < 160) ml[threadIdx.x] = mtl[(size_t)t * 256 + threadIdx.x];
    __syncthreads();
    for (int c = threadIdx.x; c < C_DIM; c += 256) {
        float a0 = 0.f, a1 = 0.f, a2 = 0.f, a3 = 0.f, a4 = 0.f;
        #pragma unroll 8
        for (int l = 0; l < 32; ++l) {
            a0 = fmaf(ml[l],       W2[(size_t)(l)       * C_DIM + c], a0);
            a1 = fmaf(ml[32 + l],  W2[(size_t)(32 + l)  * C_DIM + c], a1);
            a2 = fmaf(ml[64 + l],  W2[(size_t)(64 + l)  * C_DIM + c], a2);
            a3 = fmaf(ml[96 + l],  W2[(size_t)(96 + l)  * C_DIM + c], a3);
            a4 = fmaf(ml[128 + l], W2[(size_t)(128 + l) * C_DIM + c], a4);
        }
        size_t idx = (size_t)t * C_DIM + c;
        float xval = x[idx], sxv = sx[idx];
        xr[idx] = f2bf(xval + sxv * (tmr[c] + a0));
        xk[idx] = f2bf(xval + sxv * (tmk[c] + a1));
        xv[idx] = f2bf(xval + sxv * (tmv[c] + a2));
        xw[idx] = f2bf(xval + sxv * (tmw[c] + a3));
        xg[idx] = f2bf(xval + sxv * (tmg[c] + a4));
    }
}

// ---------------------------------------------------------------------------
// Chunked scan pass 1: per (head, chunk): P[k]=prod ew', U = chunk-local scan.
// ---------------------------------------------------------------------------
__global__ __launch_bounds__(64)
void scan_pass1(const float* __restrict__ k0, const float* __restrict__ v0,
                const float* __restrict__ dec, const unsigned char* __restrict__ ns,
                float* __restrict__ U, float* __restrict__ P) {
    int h = blockIdx.x, c = blockIdx.y, v = threadIdx.x;
    int hk = h >> 2;
    float u[64];
    #pragma unroll
    for (int k = 0; k < 64; ++k) u[k] = 0.f;
    float pk = 1.f;
    __shared__ float ew_s[64], kk_s[64];
    for (int i = 0; i < CL; ++i) {
        int t = c * CL + i;
        float dv = dec[(size_t)t * 2048 + h * 64 + v];
        float lw = fmaxf(-__expf(dv), -5.f);
        float ew = __expf(lw);
        float ewp = ns[t] ? 0.f : ew;
        ew_s[v] = ewp;
        kk_s[v] = k0[(size_t)t * 512 + hk * 64 + v] * (1.f - ew);
        __syncthreads();
        float vv = v0[(size_t)t * 512 + hk * 64 + v];
        pk *= ewp;
        #pragma unroll
        for (int k = 0; k < 64; ++k)
            u[k] = fmaf(u[k], ew_s[k], kk_s[k] * vv);
        __syncthreads();
    }
    size_t base = ((size_t)h * NC + c) * 4096;
    #pragma unroll
    for (int k = 0; k < 64; ++k) U[base + k * 64 + v] = u[k];
    P[((size_t)h * NC + c) * 64 + v] = pk;
}

// ---------------------------------------------------------------------------
// Pass 2 (elementwise-parallel): one thread per (h,k,v) state element.
// Serial over 32 chunks: start=s; s=s*P[h,c,k]+U[h,c,k,v]; U <- start (in
// place).  512 blocks x 256 threads.
// ---------------------------------------------------------------------------
__global__ __launch_bounds__(256)
void scan_pass2(float* __restrict__ U, const float* __restrict__ P,
                const float* __restrict__ state, float* __restrict__ outstate) {
    int e = blockIdx.x * 256 + threadIdx.x;      // e = h*4096 + k*64 + v
    int h = e >> 12;
    int k = (e >> 6) & 63;
    float s = state[C_DIM + e];
    int rem = e & 4095;
    #pragma unroll 4
    for (int c = 0; c < NC; ++c) {
        size_t ub = ((size_t)h * NC + c) * 4096 + rem;
        float p = P[((size_t)h * NC + c) * 64 + k];
        float u = U[ub];
        U[ub] = s;
        s = fmaf(s, p, u);
    }
    outstate[C_DIM + e] = s;
}

// ---------------------------------------------------------------------------
// Pass 3: replay chunk from start state (stored in U), emit y0b = bf16(o*g).
// ---------------------------------------------------------------------------
__global__ __launch_bounds__(64)
void scan_pass3(const float* __restrict__ r, const float* __restrict__ k0,
                const float* __restrict__ v0, const float* __restrict__ dec,
                const unsigned char* __restrict__ ns,
                const float* __restrict__ Sstarts, const float* __restrict__ g,
                ushort_t* __restrict__ y0b) {
    int h = blockIdx.x, c = blockIdx.y, v = threadIdx.x;
    int hk = h >> 2;
    float s[64];
    size_t base = ((size_t)h * NC + c) * 4096;
    #pragma unroll
    for (int k = 0; k < 64; ++k) s[k] = Sstarts[base + k * 64 + v];
    __shared__ float r_s[64], ew_s[64], kk_s[64];
    for (int i = 0; i < CL; ++i) {
        int t = c * CL + i;
        float dv = dec[(size_t)t * 2048 + h * 64 + v];
        float lw = fmaxf(-__expf(dv), -5.f);
        float ew = __expf(lw);
        ew_s[v] = ns[t] ? 0.f : ew;
        kk_s[v] = k0[(size_t)t * 512 + hk * 64 + v] * (1.f - ew);
        r_s[v]  = r[(size_t)t * 2048 + h * 64 + v];
        __syncthreads();
        float vv = v0[(size_t)t * 512 + hk * 64 + v];
        float o = 0.f;
        #pragma unroll
        for (int k = 0; k < 64; ++k) {
            float sk = fmaf(s[k], ew_s[k], kk_s[k] * vv);
            s[k] = sk;
            o = fmaf(r_s[k], sk, o);
        }
        size_t idx = (size_t)t * 2048 + h * 64 + v;
        y0b[idx] = f2bf(o * g[idx]);
        __syncthreads();
    }
}

__global__ __launch_bounds__(256)
void state0_kernel(const float* __restrict__ x, const int* __restrict__ len,
                   float* __restrict__ outstate) {
    int c = blockIdx.x * 256 + threadIdx.x;
    if (c < C_DIM)
        outstate[c] = x[(size_t)(len[0] - 1) * C_DIM + c];
}

// ---------------------------------------------------------------------------
extern "C" void kernel_launch(void* const* d_in, const int* in_sizes, int n_in,
                              void* d_out, int out_size, void* d_ws, size_t ws_size,
                              hipStream_t stream) {
    const float* x     = (const float*)d_in[0];
    const float* state = (const float*)d_in[1];
    const unsigned char* ns = (const unsigned char*)d_in[2];
    const int*   len   = (const int*)d_in[3];
    const float* tmx   = (const float*)d_in[4];
    const float* tmr   = (const float*)d_in[5];
    const float* tmk   = (const float*)d_in[6];
    const float* tmv   = (const float*)d_in[7];
    const float* tmw   = (const float*)d_in[8];
    const float* tmg   = (const float*)d_in[9];
    const float* W1    = (const float*)d_in[10];   // [C,160]
    const float* W2    = (const float*)d_in[11];   // [5,32,C] fp32 (stays)
    const float* tdec  = (const float*)d_in[12];   // [C]
    const float* Wd1   = (const float*)d_in[13];   // [C,64]
    const float* Wd2   = (const float*)d_in[14];   // [64,C]
    const float* Wq    = (const float*)d_in[15];
    const float* Wk    = (const float*)d_in[16];
    const float* Wv    = (const float*)d_in[17];
    const float* Wg    = (const float*)d_in[18];
    const float* Wo    = (const float*)d_in[19];

    float* out = (float*)d_out;
    float* outstate = out + (size_t)T_DIM * C_DIM;

    // ---- workspace layout (byte offsets; 122 MB total, aliased) ----
    char* wsb = (char*)d_ws;
    const size_t MB = 1024 * 1024;
    float*    sx   = (float*)(wsb + 0);            // 16 MB; later dec
    ushort_t* xxxb = (ushort_t*)(wsb + 16 * MB);   // 8 MB; later y0b
    float*    mtl  = (float*)(wsb + 24 * MB);      // 2 MB region
    ushort_t* tw   = (ushort_t*)(wsb + 24 * MB);   //   tw [T,128] bf16 (after mtl dead)
    float*    P    = (float*)(wsb + 25 * MB);      //   P  [32*32*64] fp32
    ushort_t* xr   = (ushort_t*)(wsb + 26 * MB);   // 8 MB
    ushort_t* xk   = (ushort_t*)(wsb + 34 * MB);   // 8 MB
    ushort_t* xv   = (ushort_t*)(wsb + 42 * MB);   // 8 MB
    ushort_t* xw   = (ushort_t*)(wsb + 50 * MB);   // 8 MB
    ushort_t* xg   = (ushort_t*)(wsb + 58 * MB);   // 8 MB  (ends 66)
    float*    g    = (float*)(wsb + 42 * MB);      // 16 MB over xv,xw
    float*    r    = (float*)(wsb + 66 * MB);      // 16 MB
    float*    k0   = (float*)(wsb + 82 * MB);      // 4 MB
    float*    v0   = (float*)(wsb + 86 * MB);      // 4 MB
    ushort_t* WqT  = (ushort_t*)(wsb + 90 * MB);   // 8 MB
    ushort_t* WkT  = (ushort_t*)(wsb + 98 * MB);   // 2 MB
    ushort_t* WvT  = (ushort_t*)(wsb + 100 * MB);  // 2 MB
    ushort_t* W1T  = (ushort_t*)(wsb + 102 * MB);  // 1 MB  [256,2048]
    ushort_t* Wd1T = (ushort_t*)(wsb + 103 * MB);  // 0.5 MB [128,2048]
    ushort_t* Wd2T = (ushort_t*)(wsb + 103 * MB + 512 * 1024); // 0.25 MB [2048,64]
    ushort_t* WgT  = (ushort_t*)(wsb + 106 * MB);  // 8 MB
    ushort_t* WoT  = (ushort_t*)(wsb + 114 * MB);  // 8 MB (ends 122)
    float*    U    = (float*)(wsb + 90 * MB);      // 16 MB over WqT..WvT (dead by pass1)
    float*    dec  = sx;
    ushort_t* y0b  = xxxb;

    dim3 blk(256);
    int nElem4 = T_DIM * C_DIM / 4;

    // ---- weight cast+transpose ----
    castT_kernel<<<dim3(8, 64), blk, 0, stream>>>(W1, W1T, 2048, 160);     // ->[256,2048]
    castT_kernel<<<dim3(4, 64), blk, 0, stream>>>(Wd1, Wd1T, 2048, 64);    // ->[128,2048]
    castT_kernel<<<dim3(64, 2), blk, 0, stream>>>(Wd2, Wd2T, 64, 2048);    // ->[2048,64]
    castT_kernel<<<dim3(64, 64), blk, 0, stream>>>(Wq, WqT, 2048, 2048);
    castT_kernel<<<dim3(16, 64), blk, 0, stream>>>(Wk, WkT, 2048, 512);
    castT_kernel<<<dim3(16, 64), blk, 0, stream>>>(Wv, WvT, 2048, 512);
    castT_kernel<<<dim3(64, 64), blk, 0, stream>>>(Wg, WgT, 2048, 2048);
    castT_kernel<<<dim3(64, 64), blk, 0, stream>>>(Wo, WoT, 2048, 2048);

    // ---- prep / LoRA ----
    prep_kernel<<<dim3((nElem4 + 255) / 256), blk, 0, stream>>>(x, state, ns, tmx, sx, xxxb);
    gemm_mfma<1><<<dim3(2, 16), blk, 0, stream>>>(xxxb, 2048, W1T, nullptr, mtl, nullptr, 256, 2048);
    maa_combine<<<dim3(T_DIM), blk, 0, stream>>>(x, sx, mtl, W2, tmr, tmk, tmv, tmw, tmg,
                                                 xr, xk, xv, xw, xg);
    // ---- projections (order matters for aliasing) ----
    gemm_mfma<4><<<dim3(1, 16), blk, 0, stream>>>(xw, 2048, Wd1T, nullptr, nullptr, tw, 128, 2048);
    gemm_mfma<0><<<dim3(4, 16), blk, 0, stream>>>(xk, 2048, WkT, nullptr, k0, nullptr, 512, 2048);
    gemm_mfma<0><<<dim3(4, 16), blk, 0, stream>>>(xv, 2048, WvT, nullptr, v0, nullptr, 512, 2048);
    gemm_mfma<0><<<dim3(16, 16), blk, 0, stream>>>(xr, 2048, WqT, nullptr, r, nullptr, 2048, 2048);
    gemm_mfma<3><<<dim3(16, 16), blk, 0, stream>>>(tw, 128, Wd2T, tdec, dec, nullptr, 2048, 64);
    gemm_mfma<2><<<dim3(16, 16), blk, 0, stream>>>(xg, 2048, WgT, nullptr, g, nullptr, 2048, 2048);
    // ---- chunked scan ----
    scan_pass1<<<dim3(NH, NC), dim3(64), 0, stream>>>(k0, v0, dec, ns, U, P);
    scan_pass2<<<dim3(512), blk, 0, stream>>>(U, P, state, outstate);
    scan_pass3<<<dim3(NH, NC), dim3(64), 0, stream>>>(r, k0, v0, dec, ns, U, g, y0b);
    // ---- output ----
    gemm_mfma<0><<<dim3(16, 16), blk, 0, stream>>>(y0b, 2048, WoT, nullptr, out, nullptr, 2048, 2048);
    state0_kernel<<<dim3(8), blk, 0, stream>>>(x, len, outstate);
}